// Round 5
// baseline (241.758 us; speedup 1.0000x reference)
//
#include <hip/hip_runtime.h>

typedef unsigned short u16;
typedef unsigned int u32;
typedef __bf16 bf16x8 __attribute__((ext_vector_type(8)));
typedef float f32x4 __attribute__((ext_vector_type(4)));

#define N_NODES 10000
#define N_EDGES 160000
#define D_IN 512
#define D_HID 1024

#define AS1 __attribute__((address_space(1)))
#define AS3 __attribute__((address_space(3)))

__device__ __forceinline__ u16 f2bf(float f) {
    union { float f; u32 u; } v; v.f = f;
    return (u16)((v.u + 0x7fffu + ((v.u >> 16) & 1u)) >> 16);
}
__device__ __forceinline__ float b2f(u32 h) {
    union { u32 u; float f; } v; v.u = h << 16; return v.f;
}

// ---- fused prep: hist (625 blk) | cvt feat->bf16 (2500 blk) | transW (1024 blk) ----
__global__ __launch_bounds__(256) void prep_k(const int* __restrict__ dst,
                                              int* __restrict__ counts,
                                              const float* __restrict__ feat,
                                              u16* __restrict__ featb,
                                              const float* __restrict__ W1,
                                              u16* __restrict__ w1t,
                                              const float* __restrict__ W2,
                                              u16* __restrict__ w2t) {
    int b = blockIdx.x;
    int t = threadIdx.x;
    if (b < 625) {                       // hist
        int e = b * 256 + t;
        if (e < N_EDGES) atomicAdd(&counts[dst[e]], 1);
        return;
    }
    if (b < 625 + 2500) {                // cvt feat -> bf16, 8/thread
        int i = ((b - 625) * 256 + t) * 8;
        float4 a = *(const float4*)(feat + i);
        float4 c = *(const float4*)(feat + i + 4);
        uint4 o;
        o.x = (u32)f2bf(a.x) | ((u32)f2bf(a.y) << 16);
        o.y = (u32)f2bf(a.z) | ((u32)f2bf(a.w) << 16);
        o.z = (u32)f2bf(c.x) | ((u32)f2bf(c.y) << 16);
        o.w = (u32)f2bf(c.z) | ((u32)f2bf(c.w) << 16);
        *(uint4*)(featb + i) = o;
        return;
    }
    // transpose+convert: WT[n][k] = bf16(W[k][n])
    __shared__ float tile[32][33];
    b -= 3125;
    const float* W; u16* WT; int K, N, nt;
    if (b < 512) { W = W1; WT = w1t; K = D_IN;  N = D_HID; nt = 32; }
    else         { b -= 512; W = W2; WT = w2t; K = D_HID; N = D_IN;  nt = 16; }
    int n0 = (b % nt) * 32, k0 = (b / nt) * 32;
    int tx = t & 31, ty = t >> 5;
#pragma unroll
    for (int i = 0; i < 32; i += 8)
        tile[ty + i][tx] = W[(size_t)(k0 + ty + i) * N + n0 + tx];
    __syncthreads();
#pragma unroll
    for (int i = 0; i < 32; i += 8)
        WT[(size_t)(n0 + ty + i) * K + k0 + tx] = f2bf(tile[tx][ty + i]);
}

// ---- single-block scan via wave shuffles: offs[10001], cursor[10000] ----
__global__ __launch_bounds__(1024) void scan_k(const int* __restrict__ counts,
                                               int* __restrict__ offs,
                                               int* __restrict__ cursor) {
    __shared__ int wpre[16];
    int t = threadIdx.x, l = t & 63, w = t >> 6;
    int base = t * 10;
    int c[10];
    int lsum = 0;
#pragma unroll
    for (int i = 0; i < 10; i++) {
        int idx = base + i;
        c[i] = (idx < N_NODES) ? counts[idx] : 0;
        lsum += c[i];
    }
    int sc = lsum;
#pragma unroll
    for (int d = 1; d < 64; d <<= 1) {
        int v = __shfl_up(sc, d);
        if (l >= d) sc += v;
    }
    __shared__ int wsum[16];
    if (l == 63) wsum[w] = sc;
    __syncthreads();
    if (w == 0 && l < 16) {
        int v = wsum[l];
        int p = v;
#pragma unroll
        for (int d = 1; d < 16; d <<= 1) {
            int u = __shfl_up(p, d);
            if (l >= d) p += u;
        }
        wpre[l] = p - v;
    }
    __syncthreads();
    int run = wpre[w] + sc - lsum;
#pragma unroll
    for (int i = 0; i < 10; i++) {
        int idx = base + i;
        if (idx < N_NODES) { offs[idx] = run; cursor[idx] = run; run += c[i]; }
    }
    if (t == 1023) offs[N_NODES] = wpre[15] + sc;
}

// ---- reorder edges into dst-sorted order ----
__global__ void reorder_k(const int* __restrict__ src, const int* __restrict__ dst,
                          int* __restrict__ cursor, int* __restrict__ ssrc) {
    int e = blockIdx.x * 256 + threadIdx.x;
    if (e >= N_EDGES) return;
    int d = dst[e];
    int pos = atomicAdd(&cursor[d], 1);
    ssrc[pos] = src[e];
}

// ---- gather-sum from bf16 feat + (1+eps)*fp32 self, write bf16 ----
__global__ __launch_bounds__(128) void gather_k(const float* __restrict__ feat,
                                                const u16* __restrict__ featb,
                                                const float* __restrict__ eps,
                                                const int* __restrict__ offs,
                                                const int* __restrict__ ssrc,
                                                u16* __restrict__ out) {
    int n = (blockIdx.x * 128 + threadIdx.x) >> 6;
    int l = threadIdx.x & 63;
    if (n >= N_NODES) return;
    int beg = offs[n], end = offs[n + 1];
    float s = 1.0f + eps[0];
    float4 s0 = *(const float4*)(feat + (size_t)n * D_IN + l * 8);
    float4 s1 = *(const float4*)(feat + (size_t)n * D_IN + l * 8 + 4);
    float acc[8] = { s * s0.x, s * s0.y, s * s0.z, s * s0.w,
                     s * s1.x, s * s1.y, s * s1.z, s * s1.w };
    int e = beg;
    for (; e + 4 <= end; e += 4) {
        int i0 = ssrc[e], i1 = ssrc[e + 1], i2 = ssrc[e + 2], i3 = ssrc[e + 3];
        uint4 v0 = *(const uint4*)(featb + (size_t)i0 * D_IN + l * 8);
        uint4 v1 = *(const uint4*)(featb + (size_t)i1 * D_IN + l * 8);
        uint4 v2 = *(const uint4*)(featb + (size_t)i2 * D_IN + l * 8);
        uint4 v3 = *(const uint4*)(featb + (size_t)i3 * D_IN + l * 8);
#define ACC4(v) \
        acc[0] += b2f(v.x & 0xffffu); acc[1] += b2f(v.x >> 16); \
        acc[2] += b2f(v.y & 0xffffu); acc[3] += b2f(v.y >> 16); \
        acc[4] += b2f(v.z & 0xffffu); acc[5] += b2f(v.z >> 16); \
        acc[6] += b2f(v.w & 0xffffu); acc[7] += b2f(v.w >> 16);
        ACC4(v0) ACC4(v1) ACC4(v2) ACC4(v3)
    }
    for (; e < end; e++) {
        int i0 = ssrc[e];
        uint4 v0 = *(const uint4*)(featb + (size_t)i0 * D_IN + l * 8);
        ACC4(v0)
    }
#undef ACC4
    uint4 o;
    o.x = (u32)f2bf(acc[0]) | ((u32)f2bf(acc[1]) << 16);
    o.y = (u32)f2bf(acc[2]) | ((u32)f2bf(acc[3]) << 16);
    o.z = (u32)f2bf(acc[4]) | ((u32)f2bf(acc[5]) << 16);
    o.w = (u32)f2bf(acc[6]) | ((u32)f2bf(acc[7]) << 16);
    *(uint4*)(out + (size_t)n * D_IN + l * 8) = o;
}

// ---- FUSED 2-layer MLP: out = (relu(A@W1+b1))@W2 + b2 + feat ----
// One block per 48-row slab (209 blocks -> 1 block/CU, ONE round). 512 thr
// (8 waves). LDS: sA = A-slab 48x512 bf16 (48KB, staged once via gload_lds,
// slot-swizzled), sH = h-slab 48x1024 bf16 (96KB, NEVER touches HBM).
// B operands (w1t/w2t, 1MB each, L2-resident in all XCDs) are read as
// 16B fragments DIRECTLY from global -- no B staging; each byte read exactly
// once per block (16 rows x 64B lines per frag instr, fully consumed).
// Swizzle convention (proven in rounds 0-4, 0 bank conflicts): slot s of
// row r holds global k-chunk s^(r&7); frag read for chunk c uses slot
// c^(r&7); r&7 == lr&7 for frag rows. Same involution on sA (write side:
// lane l of a row-stage carries source chunk l^(r&7)) and on sH (write
// side: scalar bf16 stores at slot (n>>3)^(row&7)).
// Rationale: 5 schedule variants of the split GEMMs all pinned at 40-47us
// (shape-limited per m102: K=512/1024 gives only 8-16 k-steps). Fusion
// changes the decomposition: per-CU work = one slab = ~35k cy (2MB W via
// L1 at 64B/cy = 32k cy floor, MFMA 3.7k overlapped), kills the 40MB h
// round-trip and one dispatch. Only 2 syncthreads; waves free-run inside
// phases (round-4's win). Last slab overlaps rows: duplicate rows compute
// identical values -> benign double-store.
__global__ __launch_bounds__(512) void fused_mlp_k(const u16* __restrict__ A,
                                                   const u16* __restrict__ W1T,
                                                   const float* __restrict__ b1,
                                                   const u16* __restrict__ W2T,
                                                   const float* __restrict__ b2,
                                                   const float* __restrict__ feat,
                                                   float* __restrict__ out,
                                                   int M) {
    __shared__ __bf16 sA[48 * 512];    // 49152 B
    __shared__ __bf16 sH[48 * 1024];   // 98304 B

    int row0 = blockIdx.x * 48;
    if (row0 > M - 48) row0 = M - 48;   // overlap last slab; dup rows benign
    const int t = threadIdx.x;
    const int w = t >> 6, l = t & 63;
    const int lr = l & 15, lq = l >> 4;

    // ---- stage A slab: one gload_lds per ROW (64 lanes x 16B = full 512-
    // elem row); lane l lands in slot l, carrying source chunk l^(row&7).
    // Dest wave-uniform (row base) + lane*16 linear -> constraint satisfied.
    {
#pragma unroll
        for (int q = 0; q < 6; q++) {
            const int row = w * 6 + q;
            const u16* src = A + (size_t)(row0 + row) * 512 + ((l ^ (row & 7)) * 8);
            __builtin_amdgcn_global_load_lds((const AS1 void*)src,
                                             (AS3 void*)(&sA[row * 512]), 16, 0, 0);
        }
    }
    asm volatile("s_waitcnt vmcnt(0)" ::: "memory");
    __syncthreads();

    // ---- phase 1: h = relu(A @ W1 + b1); wave w owns cols hh*512+w*64 ----
    for (int hh = 0; hh < 2; hh++) {
        const int n0 = hh * 512 + w * 64;
        f32x4 acc[3][4] = {};
        for (int kt = 0; kt < 8; kt++) {
#pragma unroll
            for (int kk = 0; kk < 64; kk += 32) {
                const int c = kt * 8 + (kk >> 3) + lq;
                bf16x8 fa[3], fb[4];
#pragma unroll
                for (int i = 0; i < 3; i++)
                    fa[i] = *(const bf16x8*)(&sA[(i * 16 + lr) * 512 + ((c ^ (lr & 7)) * 8)]);
#pragma unroll
                for (int j = 0; j < 4; j++)
                    fb[j] = *(const bf16x8*)(W1T + (size_t)(n0 + j * 16 + lr) * 512
                                             + kt * 64 + kk + lq * 8);
#pragma unroll
                for (int i = 0; i < 3; i++)
#pragma unroll
                    for (int j = 0; j < 4; j++)
                        acc[i][j] = __builtin_amdgcn_mfma_f32_16x16x32_bf16(
                            fa[i], fb[j], acc[i][j], 0, 0, 0);
            }
        }
        // relu + bias, write h to LDS with the slot swizzle (scalar b16)
#pragma unroll
        for (int i = 0; i < 3; i++)
#pragma unroll
            for (int j = 0; j < 4; j++) {
                const int n = n0 + j * 16 + lr;
                const float bv = b1[n];
#pragma unroll
                for (int r = 0; r < 4; r++) {
                    const int row = i * 16 + lq * 4 + r;
                    const float v = fmaxf(acc[i][j][r] + bv, 0.0f);
                    ((u16*)sH)[row * 1024 + (((n >> 3) ^ (row & 7)) * 8) + (n & 7)] = f2bf(v);
                }
            }
    }
    __syncthreads();

    // ---- phase 2: out = h @ W2 + b2 + feat; wave w owns cols w*64 ----
    {
        const int n0 = w * 64;
        f32x4 acc[3][4] = {};
        for (int kt = 0; kt < 16; kt++) {
#pragma unroll
            for (int kk = 0; kk < 64; kk += 32) {
                const int c = kt * 8 + (kk >> 3) + lq;
                bf16x8 fa[3], fb[4];
#pragma unroll
                for (int i = 0; i < 3; i++)
                    fa[i] = *(const bf16x8*)(&sH[(i * 16 + lr) * 1024 + ((c ^ (lr & 7)) * 8)]);
#pragma unroll
                for (int j = 0; j < 4; j++)
                    fb[j] = *(const bf16x8*)(W2T + (size_t)(n0 + j * 16 + lr) * 1024
                                             + kt * 64 + kk + lq * 8);
#pragma unroll
                for (int i = 0; i < 3; i++)
#pragma unroll
                    for (int j = 0; j < 4; j++)
                        acc[i][j] = __builtin_amdgcn_mfma_f32_16x16x32_bf16(
                            fa[i], fb[j], acc[i][j], 0, 0, 0);
            }
        }
#pragma unroll
        for (int i = 0; i < 3; i++)
#pragma unroll
            for (int j = 0; j < 4; j++) {
                const int col = n0 + j * 16 + lr;
                const float bv = b2[col];
#pragma unroll
                for (int r = 0; r < 4; r++) {
                    const int row = row0 + i * 16 + lq * 4 + r;
                    out[(size_t)row * 512 + col] =
                        acc[i][j][r] + bv + feat[(size_t)row * 512 + col];
                }
            }
    }
}

extern "C" void kernel_launch(void* const* d_in, const int* in_sizes, int n_in,
                              void* d_out, int out_size, void* d_ws, size_t ws_size,
                              hipStream_t stream) {
    const float* feat = (const float*)d_in[0];
    const float* W1   = (const float*)d_in[1];
    const float* b1   = (const float*)d_in[2];
    const float* W2   = (const float*)d_in[3];
    const float* b2   = (const float*)d_in[4];
    const float* eps  = (const float*)d_in[5];
    const int*   src  = (const int*)d_in[6];
    const int*   dst  = (const int*)d_in[7];
    float* out = (float*)d_out;

    char* ws = (char*)d_ws;
    u16* rst_b16 = (u16*)(ws);                        // 10,240,000 B
    u16* featb   = (u16*)(ws + 30720000);             // 10,240,000 B
    u16* w1t     = (u16*)(ws + 40960000);             //  1,048,576 B
    u16* w2t     = (u16*)(ws + 42008576);             //  1,048,576 B
    int* counts  = (int*)(ws + 43057152);             //     40,000 B
    int* offs    = (int*)(ws + 43097152);             //     40,004 B
    int* cursor  = (int*)(ws + 43137160);             //     40,000 B
    int* ssrc    = (int*)(ws + 43177160);             //    640,000 B

    hipMemsetAsync(counts, 0, N_NODES * sizeof(int), stream);
    // fused: hist (625) | cvt (2500) | transw (1024)
    prep_k<<<625 + 2500 + 1024, 256, 0, stream>>>(dst, counts, feat, featb,
                                                  W1, w1t, W2, w2t);
    scan_k<<<1, 1024, 0, stream>>>(counts, offs, cursor);
    reorder_k<<<(N_EDGES + 255) / 256, 256, 0, stream>>>(src, dst, cursor, ssrc);

    gather_k<<<(N_NODES + 1) / 2, 128, 0, stream>>>(feat, featb, eps, offs, ssrc, rst_b16);

    const int NB = (N_NODES + 47) / 48;  // 209 slabs (last overlaps)
    fused_mlp_k<<<NB, 512, 0, stream>>>(rst_b16, w1t, b1, w2t, b2, feat,
                                        out, N_NODES);
}

// Round 6
// 214.747 us; speedup vs baseline: 1.1258x; 1.1258x over previous
//
#include <hip/hip_runtime.h>

typedef unsigned short u16;
typedef unsigned int u32;
typedef __bf16 bf16x8 __attribute__((ext_vector_type(8)));
typedef float f32x4 __attribute__((ext_vector_type(4)));

#define N_NODES 10000
#define N_EDGES 160000
#define D_IN 512
#define D_HID 1024

#define AS1 __attribute__((address_space(1)))
#define AS3 __attribute__((address_space(3)))

__device__ __forceinline__ u16 f2bf(float f) {
    union { float f; u32 u; } v; v.f = f;
    return (u16)((v.u + 0x7fffu + ((v.u >> 16) & 1u)) >> 16);
}
__device__ __forceinline__ float b2f(u32 h) {
    union { u32 u; float f; } v; v.u = h << 16; return v.f;
}

// ---- CSR build: histogram of dst ----
__global__ void hist_k(const int* __restrict__ dst, int* __restrict__ counts) {
    int e = blockIdx.x * 256 + threadIdx.x;
    if (e < N_EDGES) atomicAdd(&counts[dst[e]], 1);
}

// ---- single-block scan via wave shuffles: offs[10001], cursor[10000] ----
__global__ __launch_bounds__(1024) void scan_k(const int* __restrict__ counts,
                                               int* __restrict__ offs,
                                               int* __restrict__ cursor) {
    __shared__ int wpre[16];
    int t = threadIdx.x, l = t & 63, w = t >> 6;
    int base = t * 10;
    int c[10];
    int lsum = 0;
#pragma unroll
    for (int i = 0; i < 10; i++) {
        int idx = base + i;
        c[i] = (idx < N_NODES) ? counts[idx] : 0;
        lsum += c[i];
    }
    int sc = lsum;
#pragma unroll
    for (int d = 1; d < 64; d <<= 1) {
        int v = __shfl_up(sc, d);
        if (l >= d) sc += v;
    }
    __shared__ int wsum[16];
    if (l == 63) wsum[w] = sc;
    __syncthreads();
    if (w == 0 && l < 16) {
        int v = wsum[l];
        int p = v;
#pragma unroll
        for (int d = 1; d < 16; d <<= 1) {
            int u = __shfl_up(p, d);
            if (l >= d) p += u;
        }
        wpre[l] = p - v;
    }
    __syncthreads();
    int run = wpre[w] + sc - lsum;
#pragma unroll
    for (int i = 0; i < 10; i++) {
        int idx = base + i;
        if (idx < N_NODES) { offs[idx] = run; cursor[idx] = run; run += c[i]; }
    }
    if (t == 1023) offs[N_NODES] = wpre[15] + sc;
}

// ---- reorder edges into dst-sorted order ----
__global__ void reorder_k(const int* __restrict__ src, const int* __restrict__ dst,
                          int* __restrict__ cursor, int* __restrict__ ssrc) {
    int e = blockIdx.x * 256 + threadIdx.x;
    if (e >= N_EDGES) return;
    int d = dst[e];
    int pos = atomicAdd(&cursor[d], 1);
    ssrc[pos] = src[e];
}

// ---- fp32 -> bf16 convert (feat copy), 8 elems/thread ----
__global__ void cvt_bf16_k(const float* __restrict__ in, u16* __restrict__ out, int n) {
    int i = (blockIdx.x * 256 + threadIdx.x) * 8;
    if (i >= n) return;
    float4 a = *(const float4*)(in + i);
    float4 b = *(const float4*)(in + i + 4);
    uint4 o;
    o.x = (u32)f2bf(a.x) | ((u32)f2bf(a.y) << 16);
    o.y = (u32)f2bf(a.z) | ((u32)f2bf(a.w) << 16);
    o.z = (u32)f2bf(b.x) | ((u32)f2bf(b.y) << 16);
    o.w = (u32)f2bf(b.z) | ((u32)f2bf(b.w) << 16);
    *(uint4*)(out + i) = o;
}

// ---- fused W1/W2 transpose+convert: WT[n][k] = bf16(W[k][n]) ----
__global__ void transw_k(const float* __restrict__ W1, u16* __restrict__ w1t,
                         const float* __restrict__ W2, u16* __restrict__ w2t) {
    __shared__ float tile[32][33];
    int b = blockIdx.x;
    const float* W; u16* WT; int K, N, nt;
    if (b < 512) { W = W1; WT = w1t; K = D_IN;  N = D_HID; nt = 32; }
    else         { b -= 512; W = W2; WT = w2t; K = D_HID; N = D_IN;  nt = 16; }
    int n0 = (b % nt) * 32, k0 = (b / nt) * 32;
    int tx = threadIdx.x, ty = threadIdx.y;
#pragma unroll
    for (int i = 0; i < 32; i += 8)
        tile[ty + i][tx] = W[(size_t)(k0 + ty + i) * N + n0 + tx];
    __syncthreads();
#pragma unroll
    for (int i = 0; i < 32; i += 8)
        WT[(size_t)(n0 + ty + i) * K + k0 + tx] = f2bf(tile[tx][ty + i]);
}

// ---- gather-sum from bf16 feat + (1+eps)*fp32 self, write bf16 ----
__global__ __launch_bounds__(128) void gather_k(const float* __restrict__ feat,
                                                const u16* __restrict__ featb,
                                                const float* __restrict__ eps,
                                                const int* __restrict__ offs,
                                                const int* __restrict__ ssrc,
                                                u16* __restrict__ out) {
    int n = (blockIdx.x * 128 + threadIdx.x) >> 6;
    int l = threadIdx.x & 63;
    if (n >= N_NODES) return;
    int beg = offs[n], end = offs[n + 1];
    float s = 1.0f + eps[0];
    float4 s0 = *(const float4*)(feat + (size_t)n * D_IN + l * 8);
    float4 s1 = *(const float4*)(feat + (size_t)n * D_IN + l * 8 + 4);
    float acc[8] = { s * s0.x, s * s0.y, s * s0.z, s * s0.w,
                     s * s1.x, s * s1.y, s * s1.z, s * s1.w };
    int e = beg;
    for (; e + 4 <= end; e += 4) {
        int i0 = ssrc[e], i1 = ssrc[e + 1], i2 = ssrc[e + 2], i3 = ssrc[e + 3];
        uint4 v0 = *(const uint4*)(featb + (size_t)i0 * D_IN + l * 8);
        uint4 v1 = *(const uint4*)(featb + (size_t)i1 * D_IN + l * 8);
        uint4 v2 = *(const uint4*)(featb + (size_t)i2 * D_IN + l * 8);
        uint4 v3 = *(const uint4*)(featb + (size_t)i3 * D_IN + l * 8);
#define ACC4(v) \
        acc[0] += b2f(v.x & 0xffffu); acc[1] += b2f(v.x >> 16); \
        acc[2] += b2f(v.y & 0xffffu); acc[3] += b2f(v.y >> 16); \
        acc[4] += b2f(v.z & 0xffffu); acc[5] += b2f(v.z >> 16); \
        acc[6] += b2f(v.w & 0xffffu); acc[7] += b2f(v.w >> 16);
        ACC4(v0) ACC4(v1) ACC4(v2) ACC4(v3)
    }
    for (; e < end; e++) {
        int i0 = ssrc[e];
        uint4 v0 = *(const uint4*)(featb + (size_t)i0 * D_IN + l * 8);
        ACC4(v0)
    }
#undef ACC4
    uint4 o;
    o.x = (u32)f2bf(acc[0]) | ((u32)f2bf(acc[1]) << 16);
    o.y = (u32)f2bf(acc[2]) | ((u32)f2bf(acc[3]) << 16);
    o.z = (u32)f2bf(acc[4]) | ((u32)f2bf(acc[5]) << 16);
    o.w = (u32)f2bf(acc[6]) | ((u32)f2bf(acc[7]) << 16);
    *(uint4*)(out + (size_t)n * D_IN + l * 8) = o;
}

// ---- FUSED 2-layer MLP: out = (relu(A@W1+b1))@W2 + b2 + feat ----
// r5 post-mortem fixes, same decomposition:
//  (a) SWAPPED MFMA operands: D = mfma(W_frag, act_frag). Proven D-layout
//      (r0-r5): m-dim (lane lq*4+r) <- FIRST operand rows, n-dim (lane lr)
//      <- SECOND operand rows. With W first, the OUTPUT COLUMN is the
//      per-lane fast dim: phase-1 h-write = 4 packed bf16 -> one 8B LDS
//      store (12/wave vs 48 scalar; kills the 963K bank conflicts); phase-2
//      epilogue = float4 stores, each wave covers a full 128B line per row
//      (kills the 3x WRITE_SIZE amplification: 62.7MB -> ~21MB).
//      Fragment READS are byte-identical to r5 (both operands use the
//      lr-row fragment mapping) -- only output indexing is re-derived.
//  (b) 1024 threads (16 waves = 4 waves/SIMD, 2x the latency cover for the
//      W-fragment global loads; r5 had 2/SIMD and Occupancy 17%).
//  (c) everything outside this kernel reverted to the r4 measured-best
//      chain (clean A/B vs 198.9us).
// LDS: sA 48x512 bf16 (48KB, staged once, slot-swizzled: slot s of row r
// holds chunk s^(r&7)), sH 48x1024 bf16 (96KB, never touches HBM, same
// swizzle). W1T/W2T (1MB each, L2-resident) read as 16B fragments direct
// from global, each byte exactly once per block.
// Phase 1: wave w owns h-cols w*64..+63 (16 waves x 64 = 1024 ✓).
// Phase 2: wave w owns out-cols w*32..+31 (16 x 32 = 512 ✓).
// Last slab overlaps rows (row0 = min(b*48, M-48)); duplicate rows compute
// identical values -> benign double-store.
__global__ __launch_bounds__(1024) void fused_mlp_k(const u16* __restrict__ A,
                                                    const u16* __restrict__ W1T,
                                                    const float* __restrict__ b1,
                                                    const u16* __restrict__ W2T,
                                                    const float* __restrict__ b2,
                                                    const float* __restrict__ feat,
                                                    float* __restrict__ out,
                                                    int M) {
    __shared__ __bf16 sA[48 * 512];    // 49152 B
    __shared__ __bf16 sH[48 * 1024];   // 98304 B

    int row0 = blockIdx.x * 48;
    if (row0 > M - 48) row0 = M - 48;
    const int t = threadIdx.x;
    const int w = t >> 6, l = t & 63;
    const int lr = l & 15, lq = l >> 4;

    // ---- stage A slab: 16 waves x 3 rows; one gload_lds per row (64 lanes
    // x 16B = full 512-elem row). Lane l -> LDS slot l (linear dest), source
    // chunk l^(row&7) -> slot s holds chunk s^(row&7). ----
#pragma unroll
    for (int q = 0; q < 3; q++) {
        const int row = w * 3 + q;
        const u16* src = A + (size_t)(row0 + row) * 512 + ((l ^ (row & 7)) * 8);
        __builtin_amdgcn_global_load_lds((const AS1 void*)src,
                                         (AS3 void*)(&sA[row * 512]), 16, 0, 0);
    }
    asm volatile("s_waitcnt vmcnt(0)" ::: "memory");
    __syncthreads();

    // ---- phase 1: h = relu(A @ W1 + b1) ----
    {
        const int n0 = w * 64;
        f32x4 acc[3][4] = {};
        for (int kt = 0; kt < 8; kt++) {
            // W fragments for both 32-k halves issued up front (8 independent
            // 16B global loads; ds_reads + MFMA issue gives them time to fly)
            bf16x8 fw[2][4];
#pragma unroll
            for (int s = 0; s < 2; s++)
#pragma unroll
                for (int j = 0; j < 4; j++)
                    fw[s][j] = *(const bf16x8*)(W1T + (size_t)(n0 + j * 16 + lr) * 512
                                                + kt * 64 + s * 32 + lq * 8);
#pragma unroll
            for (int s = 0; s < 2; s++) {
                bf16x8 fa[3];
#pragma unroll
                for (int i = 0; i < 3; i++)
                    fa[i] = *(const bf16x8*)(&sA[(i * 16 + lr) * 512
                                             + (((kt * 8 + s * 4 + lq) ^ (lr & 7)) * 8)]);
#pragma unroll
                for (int i = 0; i < 3; i++)
#pragma unroll
                    for (int j = 0; j < 4; j++)
                        acc[i][j] = __builtin_amdgcn_mfma_f32_16x16x32_bf16(
                            fw[s][j], fa[i], acc[i][j], 0, 0, 0);
            }
        }
        // h-write: lane holds 4 CONSECUTIVE h-cols (colb..colb+3) at row
        // i*16+lr -> pack to 8B, slot-swizzled (slot = chunk ^ (row&7)).
#pragma unroll
        for (int i = 0; i < 3; i++) {
            const int hrow = i * 16 + lr;
#pragma unroll
            for (int j = 0; j < 4; j++) {
                const int colb = n0 + j * 16 + lq * 4;
                float4 bv = *(const float4*)(b1 + colb);
                float v0 = fmaxf(acc[i][j][0] + bv.x, 0.0f);
                float v1 = fmaxf(acc[i][j][1] + bv.y, 0.0f);
                float v2 = fmaxf(acc[i][j][2] + bv.z, 0.0f);
                float v3 = fmaxf(acc[i][j][3] + bv.w, 0.0f);
                uint2 pv;
                pv.x = (u32)f2bf(v0) | ((u32)f2bf(v1) << 16);
                pv.y = (u32)f2bf(v2) | ((u32)f2bf(v3) << 16);
                const int slot = (colb >> 3) ^ (hrow & 7);
                *(uint2*)((u16*)sH + hrow * 1024 + slot * 8 + (colb & 7)) = pv;
            }
        }
    }
    __syncthreads();

    // ---- phase 2: out = h @ W2 + b2 + feat ----
    {
        const int n0 = w * 32;
        f32x4 acc[3][2] = {};
        for (int kt = 0; kt < 16; kt++) {
            bf16x8 fw[2][2];
#pragma unroll
            for (int s = 0; s < 2; s++)
#pragma unroll
                for (int j = 0; j < 2; j++)
                    fw[s][j] = *(const bf16x8*)(W2T + (size_t)(n0 + j * 16 + lr) * 1024
                                                + kt * 64 + s * 32 + lq * 8);
#pragma unroll
            for (int s = 0; s < 2; s++) {
                bf16x8 fh[3];
#pragma unroll
                for (int i = 0; i < 3; i++)
                    fh[i] = *(const bf16x8*)(&sH[(i * 16 + lr) * 1024
                                             + (((kt * 8 + s * 4 + lq) ^ (lr & 7)) * 8)]);
#pragma unroll
                for (int i = 0; i < 3; i++)
#pragma unroll
                    for (int j = 0; j < 2; j++)
                        acc[i][j] = __builtin_amdgcn_mfma_f32_16x16x32_bf16(
                            fw[s][j], fh[i], acc[i][j], 0, 0, 0);
            }
        }
        // epilogue: lane holds 4 consecutive out-cols at a fixed row ->
        // float4 store; wave covers cols n0..n0+31 = one full 128B line/row
#pragma unroll
        for (int i = 0; i < 3; i++) {
            const int row = row0 + i * 16 + lr;
#pragma unroll
            for (int j = 0; j < 2; j++) {
                const int colb = n0 + j * 16 + lq * 4;
                float4 bv = *(const float4*)(b2 + colb);
                float4 fv = *(const float4*)(feat + (size_t)row * 512 + colb);
                float4 o;
                o.x = acc[i][j][0] + bv.x + fv.x;
                o.y = acc[i][j][1] + bv.y + fv.y;
                o.z = acc[i][j][2] + bv.z + fv.z;
                o.w = acc[i][j][3] + bv.w + fv.w;
                *(float4*)(out + (size_t)row * 512 + colb) = o;
            }
        }
    }
}

extern "C" void kernel_launch(void* const* d_in, const int* in_sizes, int n_in,
                              void* d_out, int out_size, void* d_ws, size_t ws_size,
                              hipStream_t stream) {
    const float* feat = (const float*)d_in[0];
    const float* W1   = (const float*)d_in[1];
    const float* b1   = (const float*)d_in[2];
    const float* W2   = (const float*)d_in[3];
    const float* b2   = (const float*)d_in[4];
    const float* eps  = (const float*)d_in[5];
    const int*   src  = (const int*)d_in[6];
    const int*   dst  = (const int*)d_in[7];
    float* out = (float*)d_out;

    char* ws = (char*)d_ws;
    u16* rst_b16 = (u16*)(ws);                        // 10,240,000 B
    u16* featb   = (u16*)(ws + 30720000);             // 10,240,000 B
    u16* w1t     = (u16*)(ws + 40960000);             //  1,048,576 B
    u16* w2t     = (u16*)(ws + 42008576);             //  1,048,576 B
    int* counts  = (int*)(ws + 43057152);             //     40,000 B
    int* offs    = (int*)(ws + 43097152);             //     40,004 B
    int* cursor  = (int*)(ws + 43137160);             //     40,000 B
    int* ssrc    = (int*)(ws + 43177160);             //    640,000 B

    const int NE = N_NODES * D_IN;  // 5,120,000

    hipMemsetAsync(counts, 0, N_NODES * sizeof(int), stream);
    hist_k<<<(N_EDGES + 255) / 256, 256, 0, stream>>>(dst, counts);
    scan_k<<<1, 1024, 0, stream>>>(counts, offs, cursor);
    reorder_k<<<(N_EDGES + 255) / 256, 256, 0, stream>>>(src, dst, cursor, ssrc);

    cvt_bf16_k<<<NE / 8 / 256, 256, 0, stream>>>(feat, featb, NE);
    transw_k<<<1024, dim3(32, 8), 0, stream>>>(W1, w1t, W2, w2t);

    gather_k<<<(N_NODES + 1) / 2, 128, 0, stream>>>(feat, featb, eps, offs, ssrc, rst_b16);

    const int NB = (N_NODES + 47) / 48;  // 209 slabs (last overlaps)
    fused_mlp_k<<<NB, 1024, 0, stream>>>(rst_b16, w1t, b1, w2t, b2, feat,
                                         out, N_NODES);
}

// Round 8
// 212.968 us; speedup vs baseline: 1.1352x; 1.0084x over previous
//
#include <hip/hip_runtime.h>

typedef unsigned short u16;
typedef unsigned int u32;
typedef __bf16 bf16x8 __attribute__((ext_vector_type(8)));
typedef float f32x4 __attribute__((ext_vector_type(4)));

#define N_NODES 10000
#define N_EDGES 160000
#define D_IN 512
#define D_HID 1024

#define AS1 __attribute__((address_space(1)))
#define AS3 __attribute__((address_space(3)))

// padded LDS row pitches (in bf16 elems): +8 elems = +16B = +4 banks/row
#define PA 520    // sA: 512 + 8
#define PH 1032   // sH: 1024 + 8

__device__ __forceinline__ u16 f2bf(float f) {
    union { float f; u32 u; } v; v.f = f;
    return (u16)((v.u + 0x7fffu + ((v.u >> 16) & 1u)) >> 16);
}
__device__ __forceinline__ float b2f(u32 h) {
    union { u32 u; float f; } v; v.u = h << 16; return v.f;
}

// ---- CSR build: histogram of dst ----
__global__ void hist_k(const int* __restrict__ dst, int* __restrict__ counts) {
    int e = blockIdx.x * 256 + threadIdx.x;
    if (e < N_EDGES) atomicAdd(&counts[dst[e]], 1);
}

// ---- single-block scan via wave shuffles: offs[10001], cursor[10000] ----
__global__ __launch_bounds__(1024) void scan_k(const int* __restrict__ counts,
                                               int* __restrict__ offs,
                                               int* __restrict__ cursor) {
    __shared__ int wpre[16];
    int t = threadIdx.x, l = t & 63, w = t >> 6;
    int base = t * 10;
    int c[10];
    int lsum = 0;
#pragma unroll
    for (int i = 0; i < 10; i++) {
        int idx = base + i;
        c[i] = (idx < N_NODES) ? counts[idx] : 0;
        lsum += c[i];
    }
    int sc = lsum;
#pragma unroll
    for (int d = 1; d < 64; d <<= 1) {
        int v = __shfl_up(sc, d);
        if (l >= d) sc += v;
    }
    __shared__ int wsum[16];
    if (l == 63) wsum[w] = sc;
    __syncthreads();
    if (w == 0 && l < 16) {
        int v = wsum[l];
        int p = v;
#pragma unroll
        for (int d = 1; d < 16; d <<= 1) {
            int u = __shfl_up(p, d);
            if (l >= d) p += u;
        }
        wpre[l] = p - v;
    }
    __syncthreads();
    int run = wpre[w] + sc - lsum;
#pragma unroll
    for (int i = 0; i < 10; i++) {
        int idx = base + i;
        if (idx < N_NODES) { offs[idx] = run; cursor[idx] = run; run += c[i]; }
    }
    if (t == 1023) offs[N_NODES] = wpre[15] + sc;
}

// ---- reorder edges into dst-sorted order ----
__global__ void reorder_k(const int* __restrict__ src, const int* __restrict__ dst,
                          int* __restrict__ cursor, int* __restrict__ ssrc) {
    int e = blockIdx.x * 256 + threadIdx.x;
    if (e >= N_EDGES) return;
    int d = dst[e];
    int pos = atomicAdd(&cursor[d], 1);
    ssrc[pos] = src[e];
}

// ---- fp32 -> bf16 convert (feat copy), 8 elems/thread ----
__global__ void cvt_bf16_k(const float* __restrict__ in, u16* __restrict__ out, int n) {
    int i = (blockIdx.x * 256 + threadIdx.x) * 8;
    if (i >= n) return;
    float4 a = *(const float4*)(in + i);
    float4 b = *(const float4*)(in + i + 4);
    uint4 o;
    o.x = (u32)f2bf(a.x) | ((u32)f2bf(a.y) << 16);
    o.y = (u32)f2bf(a.z) | ((u32)f2bf(a.w) << 16);
    o.z = (u32)f2bf(b.x) | ((u32)f2bf(b.y) << 16);
    o.w = (u32)f2bf(b.z) | ((u32)f2bf(b.w) << 16);
    *(uint4*)(out + i) = o;
}

// ---- fused W1/W2 transpose+convert: WT[n][k] = bf16(W[k][n]) ----
__global__ void transw_k(const float* __restrict__ W1, u16* __restrict__ w1t,
                         const float* __restrict__ W2, u16* __restrict__ w2t) {
    __shared__ float tile[32][33];
    int b = blockIdx.x;
    const float* W; u16* WT; int K, N, nt;
    if (b < 512) { W = W1; WT = w1t; K = D_IN;  N = D_HID; nt = 32; }
    else         { b -= 512; W = W2; WT = w2t; K = D_HID; N = D_IN;  nt = 16; }
    int n0 = (b % nt) * 32, k0 = (b / nt) * 32;
    int tx = threadIdx.x, ty = threadIdx.y;
#pragma unroll
    for (int i = 0; i < 32; i += 8)
        tile[ty + i][tx] = W[(size_t)(k0 + ty + i) * N + n0 + tx];
    __syncthreads();
#pragma unroll
    for (int i = 0; i < 32; i += 8)
        WT[(size_t)(n0 + ty + i) * K + k0 + tx] = f2bf(tile[tx][ty + i]);
}

// ---- gather-sum from bf16 feat + (1+eps)*fp32 self, write bf16 ----
__global__ __launch_bounds__(128) void gather_k(const float* __restrict__ feat,
                                                const u16* __restrict__ featb,
                                                const float* __restrict__ eps,
                                                const int* __restrict__ offs,
                                                const int* __restrict__ ssrc,
                                                u16* __restrict__ out) {
    int n = (blockIdx.x * 128 + threadIdx.x) >> 6;
    int l = threadIdx.x & 63;
    if (n >= N_NODES) return;
    int beg = offs[n], end = offs[n + 1];
    float s = 1.0f + eps[0];
    float4 s0 = *(const float4*)(feat + (size_t)n * D_IN + l * 8);
    float4 s1 = *(const float4*)(feat + (size_t)n * D_IN + l * 8 + 4);
    float acc[8] = { s * s0.x, s * s0.y, s * s0.z, s * s0.w,
                     s * s1.x, s * s1.y, s * s1.z, s * s1.w };
    int e = beg;
    for (; e + 4 <= end; e += 4) {
        int i0 = ssrc[e], i1 = ssrc[e + 1], i2 = ssrc[e + 2], i3 = ssrc[e + 3];
        uint4 v0 = *(const uint4*)(featb + (size_t)i0 * D_IN + l * 8);
        uint4 v1 = *(const uint4*)(featb + (size_t)i1 * D_IN + l * 8);
        uint4 v2 = *(const uint4*)(featb + (size_t)i2 * D_IN + l * 8);
        uint4 v3 = *(const uint4*)(featb + (size_t)i3 * D_IN + l * 8);
#define ACC4(v) \
        acc[0] += b2f(v.x & 0xffffu); acc[1] += b2f(v.x >> 16); \
        acc[2] += b2f(v.y & 0xffffu); acc[3] += b2f(v.y >> 16); \
        acc[4] += b2f(v.z & 0xffffu); acc[5] += b2f(v.z >> 16); \
        acc[6] += b2f(v.w & 0xffffu); acc[7] += b2f(v.w >> 16);
        ACC4(v0) ACC4(v1) ACC4(v2) ACC4(v3)
    }
    for (; e < end; e++) {
        int i0 = ssrc[e];
        uint4 v0 = *(const uint4*)(featb + (size_t)i0 * D_IN + l * 8);
        ACC4(v0)
    }
#undef ACC4
    uint4 o;
    o.x = (u32)f2bf(acc[0]) | ((u32)f2bf(acc[1]) << 16);
    o.y = (u32)f2bf(acc[2]) | ((u32)f2bf(acc[3]) << 16);
    o.z = (u32)f2bf(acc[4]) | ((u32)f2bf(acc[5]) << 16);
    o.w = (u32)f2bf(acc[6]) | ((u32)f2bf(acc[7]) << 16);
    *(uint4*)(out + (size_t)n * D_IN + l * 8) = o;
}

// ---- FUSED 2-layer MLP: out = (relu(A@W1+b1))@W2 + b2 + feat ----
// r7 resubmission, HARDENED: r7's bench died in the container (no counters).
// Possible real cause: the prologue's hand-counted `s_waitcnt vmcnt(4)` --
// the compiler may reorder other VMEM loads before the 3 global_load_lds,
// making the count not cover the stagings (waves read un-staged LDS).
// Fix: plain __syncthreads() at both sync points (full drain, provably
// correct; costs ~2x300cy ONCE per kernel = noise). The r7 levers kept:
//  (a) PADDED LDS rows (PA=520, PH=1032; +16B/row) replace all XOR swizzles
//      -> kills r6's 2.09M bank conflicts (stride-2048B aliasing).
//  (b) DEPTH-1 ROLLING W PREFETCH: next s-half's W fragments loaded before
//      current half's MFMAs; compiler tracks the register deps itself (no
//      fragile waitcnt counting). r6 loaded W per-kt and consumed
//      immediately -> ~300cy L2 latency exposed per kt (MfmaUtil 10%).
//  (c) s_setprio(1) around MFMA clusters (waves here phase-desync).
// LDS: sA 48xPA (49,920B) + sH 48xPH (99,072B) = 148,992B -> 1 block/CU.
// Phase 1: wave w owns h-cols w*64..+63; phase 2: out-cols w*32..+31.
// D-layout (proven passing in r6): D = mfma(W_frag, act_frag) -> out-col =
// lane lq*4+r (packed h/out stores), act-row = lane lr.
// Last slab overlaps rows; duplicate rows -> benign double-store.
__global__ __launch_bounds__(1024) void fused_mlp_k(const u16* __restrict__ A,
                                                    const u16* __restrict__ W1T,
                                                    const float* __restrict__ b1,
                                                    const u16* __restrict__ W2T,
                                                    const float* __restrict__ b2,
                                                    const float* __restrict__ feat,
                                                    float* __restrict__ out,
                                                    int M) {
    __shared__ __bf16 sA[48 * PA];
    __shared__ __bf16 sH[48 * PH];

    int row0 = blockIdx.x * 48;
    if (row0 > M - 48) row0 = M - 48;
    const int t = threadIdx.x;
    const int w = t >> 6, l = t & 63;
    const int lr = l & 15, lq = l >> 4;

    // ---- stage A slab: 16 waves x 3 rows; one gload_lds per row (64 lanes
    // x 16B = the full 512-elem row; pad untouched). Linear, no swizzle. ----
#pragma unroll
    for (int q = 0; q < 3; q++) {
        const int row = w * 3 + q;
        const u16* src = A + (size_t)(row0 + row) * 512 + l * 8;
        __builtin_amdgcn_global_load_lds((const AS1 void*)src,
                                         (AS3 void*)(&sA[row * PA]), 16, 0, 0);
    }
    // full drain + barrier: provably correct (graph-capture-safe, no counted
    // vmcnt hazard); one-time cost only
    __syncthreads();

    // ---- phase 1: h = relu(A @ W1 + b1) ----
    const int n1 = w * 64;
    {
        // first W fragments (kt=0, s=0)
        bf16x8 fw[4];
#pragma unroll
        for (int j = 0; j < 4; j++)
            fw[j] = *(const bf16x8*)(W1T + (size_t)(n1 + j * 16 + lr) * 512 + lq * 8);

        f32x4 acc[3][4] = {};
#pragma unroll 2
        for (int kt = 0; kt < 8; kt++) {
#pragma unroll
            for (int s = 0; s < 2; s++) {
                // rolling prefetch of the NEXT half's W fragments
                bf16x8 fwn[4];
                const int nkt = s ? kt + 1 : kt;
                const int ns = s ? 0 : 1;
                if (nkt < 8) {
#pragma unroll
                    for (int j = 0; j < 4; j++)
                        fwn[j] = *(const bf16x8*)(W1T
                            + (size_t)(n1 + j * 16 + lr) * 512
                            + nkt * 64 + ns * 32 + lq * 8);
                }
                bf16x8 fa[3];
#pragma unroll
                for (int i = 0; i < 3; i++)
                    fa[i] = *(const bf16x8*)(&sA[(i * 16 + lr) * PA
                                             + (kt * 64 + s * 32 + lq * 8)]);
                __builtin_amdgcn_s_setprio(1);
#pragma unroll
                for (int i = 0; i < 3; i++)
#pragma unroll
                    for (int j = 0; j < 4; j++)
                        acc[i][j] = __builtin_amdgcn_mfma_f32_16x16x32_bf16(
                            fw[j], fa[i], acc[i][j], 0, 0, 0);
                __builtin_amdgcn_s_setprio(0);
#pragma unroll
                for (int j = 0; j < 4; j++) fw[j] = fwn[j];
            }
        }
        // h-write: lane holds 4 consecutive h-cols at row i*16+lr -> one
        // 8B packed store into the padded row (no swizzle)
#pragma unroll
        for (int i = 0; i < 3; i++) {
            const int hrow = i * 16 + lr;
#pragma unroll
            for (int j = 0; j < 4; j++) {
                const int colb = n1 + j * 16 + lq * 4;
                float4 bv = *(const float4*)(b1 + colb);
                float v0 = fmaxf(acc[i][j][0] + bv.x, 0.0f);
                float v1 = fmaxf(acc[i][j][1] + bv.y, 0.0f);
                float v2 = fmaxf(acc[i][j][2] + bv.z, 0.0f);
                float v3 = fmaxf(acc[i][j][3] + bv.w, 0.0f);
                uint2 pv;
                pv.x = (u32)f2bf(v0) | ((u32)f2bf(v1) << 16);
                pv.y = (u32)f2bf(v2) | ((u32)f2bf(v3) << 16);
                *(uint2*)((u16*)sH + hrow * PH + colb) = pv;
            }
        }
    }
    // full drain + barrier (h-stores visible to all waves)
    __syncthreads();

    // ---- phase 2: out = h @ W2 + b2 + feat ----
    const int n2 = w * 32;
    {
        bf16x8 gw[2];
#pragma unroll
        for (int j = 0; j < 2; j++)
            gw[j] = *(const bf16x8*)(W2T + (size_t)(n2 + j * 16 + lr) * 1024 + lq * 8);

        f32x4 acc[3][2] = {};
#pragma unroll 2
        for (int kt = 0; kt < 16; kt++) {
#pragma unroll
            for (int s = 0; s < 2; s++) {
                bf16x8 gwn[2];
                const int nkt = s ? kt + 1 : kt;
                const int ns = s ? 0 : 1;
                if (nkt < 16) {
#pragma unroll
                    for (int j = 0; j < 2; j++)
                        gwn[j] = *(const bf16x8*)(W2T
                            + (size_t)(n2 + j * 16 + lr) * 1024
                            + nkt * 64 + ns * 32 + lq * 8);
                }
                bf16x8 fh[3];
#pragma unroll
                for (int i = 0; i < 3; i++)
                    fh[i] = *(const bf16x8*)(&sH[(i * 16 + lr) * PH
                                             + (kt * 64 + s * 32 + lq * 8)]);
                __builtin_amdgcn_s_setprio(1);
#pragma unroll
                for (int i = 0; i < 3; i++)
#pragma unroll
                    for (int j = 0; j < 2; j++)
                        acc[i][j] = __builtin_amdgcn_mfma_f32_16x16x32_bf16(
                            gw[j], fh[i], acc[i][j], 0, 0, 0);
                __builtin_amdgcn_s_setprio(0);
#pragma unroll
                for (int j = 0; j < 2; j++) gw[j] = gwn[j];
            }
        }
        // epilogue: float4 stores; wave covers cols n2..n2+31 per row
#pragma unroll
        for (int i = 0; i < 3; i++) {
            const int row = row0 + i * 16 + lr;
#pragma unroll
            for (int j = 0; j < 2; j++) {
                const int colb = n2 + j * 16 + lq * 4;
                float4 bv = *(const float4*)(b2 + colb);
                float4 fv = *(const float4*)(feat + (size_t)row * 512 + colb);
                float4 o;
                o.x = acc[i][j][0] + bv.x + fv.x;
                o.y = acc[i][j][1] + bv.y + fv.y;
                o.z = acc[i][j][2] + bv.z + fv.z;
                o.w = acc[i][j][3] + bv.w + fv.w;
                *(float4*)(out + (size_t)row * 512 + colb) = o;
            }
        }
    }
}

extern "C" void kernel_launch(void* const* d_in, const int* in_sizes, int n_in,
                              void* d_out, int out_size, void* d_ws, size_t ws_size,
                              hipStream_t stream) {
    const float* feat = (const float*)d_in[0];
    const float* W1   = (const float*)d_in[1];
    const float* b1   = (const float*)d_in[2];
    const float* W2   = (const float*)d_in[3];
    const float* b2   = (const float*)d_in[4];
    const float* eps  = (const float*)d_in[5];
    const int*   src  = (const int*)d_in[6];
    const int*   dst  = (const int*)d_in[7];
    float* out = (float*)d_out;

    char* ws = (char*)d_ws;
    u16* rst_b16 = (u16*)(ws);                        // 10,240,000 B
    u16* featb   = (u16*)(ws + 30720000);             // 10,240,000 B
    u16* w1t     = (u16*)(ws + 40960000);             //  1,048,576 B
    u16* w2t     = (u16*)(ws + 42008576);             //  1,048,576 B
    int* counts  = (int*)(ws + 43057152);             //     40,000 B
    int* offs    = (int*)(ws + 43097152);             //     40,004 B
    int* cursor  = (int*)(ws + 43137160);             //     40,000 B
    int* ssrc    = (int*)(ws + 43177160);             //    640,000 B

    const int NE = N_NODES * D_IN;  // 5,120,000

    hipMemsetAsync(counts, 0, N_NODES * sizeof(int), stream);
    hist_k<<<(N_EDGES + 255) / 256, 256, 0, stream>>>(dst, counts);
    scan_k<<<1, 1024, 0, stream>>>(counts, offs, cursor);
    reorder_k<<<(N_EDGES + 255) / 256, 256, 0, stream>>>(src, dst, cursor, ssrc);

    cvt_bf16_k<<<NE / 8 / 256, 256, 0, stream>>>(feat, featb, NE);
    transw_k<<<1024, dim3(32, 8), 0, stream>>>(W1, w1t, W2, w2t);

    gather_k<<<(N_NODES + 1) / 2, 128, 0, stream>>>(feat, featb, eps, offs, ssrc, rst_b16);

    const int NB = (N_NODES + 47) / 48;  // 209 slabs (last overlaps)
    fused_mlp_k<<<NB, 1024, 0, stream>>>(rst_b16, w1t, b1, w2t, b2, feat,
                                         out, N_NODES);
}